// Round 4
// baseline (216.459 us; speedup 1.0000x reference)
//
#include <hip/hip_runtime.h>
#include <hip/hip_bf16.h>
#include <math.h>
#include <stdint.h>

#define BATCH 2
#define NH 12
#define SEQ 2048
#define HD 64
#define TQ 64
#define TK 64
#define NHEADS (BATCH*NH)
#define NIT (SEQ / TK)
#define NBLK (NHEADS * (SEQ / TQ))   // 768 blocks, exactly 3/CU (LDS-capped)

typedef short bf16x8 __attribute__((ext_vector_type(8)));
typedef float f32x4 __attribute__((ext_vector_type(4)));
typedef float f32x16 __attribute__((ext_vector_type(16)));
typedef unsigned short us4_t __attribute__((ext_vector_type(4)));
typedef unsigned short us8_t __attribute__((ext_vector_type(8)));
typedef unsigned int u32x4 __attribute__((ext_vector_type(4)));

#if __has_builtin(__builtin_amdgcn_exp2f)
#define EXP2F(x) __builtin_amdgcn_exp2f(x)
#else
#define EXP2F(x) exp2f(x)
#endif

static __device__ __forceinline__ unsigned short f2bf(float f) {
    unsigned int u = __float_as_uint(f);
    u += 0x7fffu + ((u >> 16) & 1u);   // RTNE
    return (unsigned short)(u >> 16);
}

static __device__ __forceinline__ unsigned int pack2bf(float a, float b) {
    __hip_bfloat162 v = __float22bfloat162_rn(float2{a, b});
    return *(unsigned int*)&v;          // low short = a
}

static __device__ __forceinline__ void async_cp16(const void* g, void* l) {
    __builtin_amdgcn_global_load_lds(
        (const __attribute__((address_space(1))) void*)g,
        (__attribute__((address_space(3))) void*)(uintptr_t)l,
        16, 0, 0);
}

// Conflict-free 64x64-bf16 tile layout: 32 row-pairs x 256B, 16 positions of
// 16B, pos = ((r&1)*8 | c) ^ ((r>>1)&15).
static __device__ __forceinline__ int tile_off(int r, int c) {   // shorts, c 0..7
    int rp  = r >> 1;
    int pos = (((r & 1) << 3) | c) ^ (rp & 15);
    return rp * 128 + pos * 8;
}

// ---------------- fused kernel: prep phase + grid barrier + FA main ----------
// R10: prep_kv is merged into the main kernel (prep grid was identical 768x256).
// All 768 blocks are provably co-resident: LDS 48.5 KB caps at 3 blocks/CU and
// grid = 256 CUs x 3. Device-scope atomic barrier with agent fences replaces
// the kernel boundary (fences do the cross-XCD L2 writeback/invalidate; the
// poison fill leaves stale ws lines in consumer-XCD L2s, so the acquire
// invalidate is required for correctness). Q staging is done BEFORE the spin,
// hiding it under the slowest block's prep. Main loop = R9 (deferred-PV
// pipeline, triple-buffered staging, counted vmcnt).
__global__ __launch_bounds__(256, 3)
void fa_all(const float* __restrict__ Q, const float* __restrict__ K,
            const float* __restrict__ V,
            unsigned short* __restrict__ Kb, unsigned short* __restrict__ Vtb,
            unsigned int* __restrict__ cnt, float* __restrict__ O, float qs) {
    __shared__ __align__(16) unsigned char SH[49664];
    const int tid = threadIdx.x;

    // ---------------- phase 1: prep slice (K->bf16, V->transposed-pi) -------
    {
        unsigned short (*T)[66] = (unsigned short (*)[66])SH;
        const int bhp = blockIdx.x >> 5;
        const int s0p = (blockIdx.x & 31) * 64;
        const size_t offp = ((size_t)bhp * SEQ + s0p) * HD;

        #pragma unroll
        for (int u = 0; u < 4; ++u) {             // K: dense 16B loads, 8B stores
            int idx = u * 1024 + tid * 4;
            float4 a = *(const float4*)&K[offp + idx];
            us4_t r4 = { f2bf(a.x), f2bf(a.y), f2bf(a.z), f2bf(a.w) };
            *(us4_t*)&Kb[offp + idx] = r4;
        }
        #pragma unroll
        for (int u = 0; u < 4; ++u) {             // V: dense loads -> padded LDS
            int idx = u * 1024 + tid * 4;
            int r = idx >> 6, col = idx & 63;
            float4 a = *(const float4*)&V[offp + idx];
            *(unsigned int*)&T[r][col]     = pack2bf(a.x, a.y);
            *(unsigned int*)&T[r][col + 2] = pack2bf(a.z, a.w);
        }
        __syncthreads();
        unsigned short* Vdst = Vtb + (size_t)bhp * HD * SEQ;
        const int g = tid & 7, dd = tid >> 3;     // dd 0..31
        #pragma unroll
        for (int h = 0; h < 2; ++h) {
            int d = dd + 32 * h;
            us8_t r8;
            #pragma unroll
            for (int j = 0; j < 8; ++j) {
                // pi: swap bits 2,3 of the 64-local column index (g*8 + j)
                int src = ((g >> 1) << 4) + ((j >> 2) << 3) + ((g & 1) << 2) + (j & 3);
                r8[j] = T[src][d];
            }
            *(us8_t*)&Vdst[(size_t)d * SEQ + s0p + g * 8] = r8;
        }
    }

    // ---------------- FA indices ----------------
    const int x  = blockIdx.x & 7;
    const int t  = blockIdx.x >> 3;
    const int bh = x + 8 * (t % 3);
    const int qt = t / 3;
    const int q0 = qt * TQ;

    float* Lsum = (float*)(SH + 49152);                    // 64 f32
    float* Linv = (float*)(SH + 49408);                    // 64 f32
    float* ORed = (float*)SH;                              // 64x64 f32 overlay (buf0)
    unsigned short* QS = (unsigned short*)(SH + 32768);    // Q staging (buf2 K half)

    const int w    = tid >> 6;
    const int mt   = w >> 1;
    const int nt   = w & 1;
    const int lane = tid & 63;
    const int l31  = lane & 31;
    const int hi   = lane >> 5;

    const float*          Qh = Q   + ((size_t)bh * SEQ + q0) * HD;
    const unsigned short* Kh = Kb  + (size_t)bh * SEQ * HD;
    const unsigned short* Vh = Vtb + (size_t)bh * HD * SEQ;

    // ---- per-lane staging source offsets (loop-invariant) ----
    int rS[2], cS[2];
    #pragma unroll
    for (int i = 0; i < 2; ++i) {
        int rp = w * 8 + 4 * i + (lane >> 4);
        int lc = (lane & 15) ^ (rp & 15);
        rS[i] = 2 * rp + (lc >> 3);
        cS[i] = lc & 7;
    }
    const int dst0 = (w * 8 + 0) * 128, dst1 = (w * 8 + 4) * 128;  // shorts
    const size_t kG0 = (size_t)rS[0] * HD  + cS[0] * 8;
    const size_t kG1 = (size_t)rS[1] * HD  + cS[1] * 8;
    const size_t vG0 = (size_t)rS[0] * SEQ + cS[0] * 8;
    const size_t vG1 = (size_t)rS[1] * SEQ + cS[1] * 8;

    // ---------------- phase 2: Q staging (independent of prep outputs) ------
    // QS region (SH+32768) is disjoint from prep's T (SH+0..8448).
    #pragma unroll
    for (int u = 0; u < 4; ++u) {
        int idx = u * 1024 + tid * 4;
        int r = idx >> 6, col = idx & 63;
        float4 a = *(const float4*)&Qh[idx];
        uint2 pk = { pack2bf(a.x * qs, a.y * qs), pack2bf(a.z * qs, a.w * qs) };
        *(uint2*)&QS[tile_off(r, col >> 3) + (col & 7)] = pk;
    }
    __syncthreads();   // QS complete (and prep T reads long done)

    bf16x8 qf[4];
    #pragma unroll
    for (int s = 0; s < 4; ++s)
        qf[s] = *(const bf16x8*)&QS[tile_off(mt * 32 + l31, s * 2 + hi)];
    __syncthreads();   // qf extracted; buf2 free for prefetch after barrier

    // ---------------- phase 3: device-scope grid barrier --------------------
    // Release: publish this block's Kb/Vtb stores (L2 writeback). Acquire:
    // invalidate stale (poison-fill) lines before reading other XCDs' output.
    if (tid == 0) {
        __builtin_amdgcn_fence(__ATOMIC_RELEASE, "agent");
        __hip_atomic_fetch_add(cnt, 1u, __ATOMIC_RELEASE, __HIP_MEMORY_SCOPE_AGENT);
        while (__hip_atomic_load(cnt, __ATOMIC_ACQUIRE, __HIP_MEMORY_SCOPE_AGENT)
               < (unsigned int)NBLK) {
            __builtin_amdgcn_s_sleep(8);
        }
        __builtin_amdgcn_fence(__ATOMIC_ACQUIRE, "agent");
    }
    __syncthreads();   // whole block released with caches clean

    // ---------------- phase 4: prefetch tiles 0,1 + main loop (R9) ----------
    {
        unsigned short* K0 = (unsigned short*)(SH);
        unsigned short* V0 = (unsigned short*)(SH + 8192);
        async_cp16(Kh + kG0, &K0[dst0]);
        async_cp16(Kh + kG1, &K0[dst1]);
        async_cp16(Vh + vG0, &V0[dst0]);
        async_cp16(Vh + vG1, &V0[dst1]);
        unsigned short* K1 = (unsigned short*)(SH + 16384);
        unsigned short* V1 = (unsigned short*)(SH + 16384 + 8192);
        async_cp16(Kh + (size_t)TK * HD + kG0, &K1[dst0]);
        async_cp16(Kh + (size_t)TK * HD + kG1, &K1[dst1]);
        async_cp16(Vh + (size_t)TK + vG0,      &V1[dst0]);
        async_cp16(Vh + (size_t)TK + vG1,      &V1[dst1]);
    }
    asm volatile("s_waitcnt vmcnt(4)" ::: "memory");   // own tile-0 loads done
    __builtin_amdgcn_s_barrier();                      // all waves' tile 0 resident

    // ---- hoisted fragment LDS offsets ----
    int kOffL[4], vOffL[2][2];
    #pragma unroll
    for (int s = 0; s < 4; ++s) kOffL[s] = tile_off(nt * 32 + l31, s * 2 + hi);
    #pragma unroll
    for (int dt = 0; dt < 2; ++dt)
        #pragma unroll
        for (int ks = 0; ks < 2; ++ks)
            vOffL[dt][ks] = tile_off(dt * 32 + l31, nt * 4 + ks * 2 + hi);

    f32x16 o[2];
    o[0] = (f32x16)(0.f);
    o[1] = (f32x16)(0.f);
    float lsum = 0.f;

    // deferred finish of a tile: exp2 + pack + PV + lsum (all register-local)
    auto FIN = [&](const f32x16& sp, const bf16x8 (&vp)[2][2]) {
        float e0[8], e1[8];
        #pragma unroll
        for (int r = 0; r < 8; ++r) e0[r] = EXP2F(sp[r]);
        #pragma unroll
        for (int r = 0; r < 8; ++r) e1[r] = EXP2F(sp[8 + r]);
        union { u32x4 d; bf16x8 h; } pu0, pu1;
        pu0.d = (u32x4){ pack2bf(e0[0], e0[1]), pack2bf(e0[2], e0[3]),
                         pack2bf(e0[4], e0[5]), pack2bf(e0[6], e0[7]) };
        pu1.d = (u32x4){ pack2bf(e1[0], e1[1]), pack2bf(e1[2], e1[3]),
                         pack2bf(e1[4], e1[5]), pack2bf(e1[6], e1[7]) };
        bf16x8 pf0 = pu0.h, pf1 = pu1.h;
        o[0] = __builtin_amdgcn_mfma_f32_32x32x16_bf16(pf0, vp[0][0], o[0], 0, 0, 0);
        o[1] = __builtin_amdgcn_mfma_f32_32x32x16_bf16(pf0, vp[1][0], o[1], 0, 0, 0);
        o[0] = __builtin_amdgcn_mfma_f32_32x32x16_bf16(pf1, vp[0][1], o[0], 0, 0, 0);
        o[1] = __builtin_amdgcn_mfma_f32_32x32x16_bf16(pf1, vp[1][1], o[1], 0, 0, 0);
        float t0 = ((e0[0] + e0[1]) + (e0[2] + e0[3]))
                 + ((e0[4] + e0[5]) + (e0[6] + e0[7]));
        float t1 = ((e1[0] + e1[1]) + (e1[2] + e1[3]))
                 + ((e1[4] + e1[5]) + (e1[6] + e1[7]));
        lsum += t0 + t1;
    };

    unsigned int b0 = 0, b1 = 16384, b2 = 32768;   // rotating buffer byte offsets

    // pipeline state: scores + V fragments of the previous tile
    f32x16 scp;
    bf16x8 vfp[2][2];

    // ---- peeled iteration 0: tile 0 resident, all waves synced ----
    {
        // prefetch tile 2 into buf2 (old QS — qf already extracted)
        unsigned short* Kn = (unsigned short*)(SH + b2);
        unsigned short* Vn = (unsigned short*)(SH + b2 + 8192);
        async_cp16(Kh + (size_t)2 * TK * HD + kG0, &Kn[dst0]);
        async_cp16(Kh + (size_t)2 * TK * HD + kG1, &Kn[dst1]);
        async_cp16(Vh + (size_t)2 * TK + vG0,      &Vn[dst0]);
        async_cp16(Vh + (size_t)2 * TK + vG1,      &Vn[dst1]);

        const unsigned short* Ks = (const unsigned short*)(SH + b0);
        const unsigned short* Vs = (const unsigned short*)(SH + b0 + 8192);
        #pragma unroll
        for (int dt = 0; dt < 2; ++dt)
            #pragma unroll
            for (int ks = 0; ks < 2; ++ks)
                vfp[dt][ks] = *(const bf16x8*)&Vs[vOffL[dt][ks]];
        f32x16 sc = (f32x16)(0.f);
        #pragma unroll
        for (int s = 0; s < 4; ++s) {
            bf16x8 kf = *(const bf16x8*)&Ks[kOffL[s]];
            sc = __builtin_amdgcn_mfma_f32_32x32x16_bf16(kf, qf[s], sc, 0, 0, 0);
        }
        scp = sc;
        unsigned int btmp = b0; b0 = b1; b1 = b2; b2 = btmp;
    }

    // ---- main loop: iter t computes QK(t) and finishes tile t-1 ----
    #pragma unroll 2
    for (int it = 1; it < NIT; ++it) {
        // all my ds_reads (incl. deferred V frags) complete before the barrier,
        // so the post-barrier prefetch into buf[(it+2)%3] cannot race them.
        asm volatile("s_waitcnt lgkmcnt(0)" ::: "memory");
        if (it == NIT - 1) { asm volatile("s_waitcnt vmcnt(0)" ::: "memory"); }
        else               { asm volatile("s_waitcnt vmcnt(4)" ::: "memory"); }
        __builtin_amdgcn_s_barrier();   // all waves: tile it resident

        if (it + 2 < NIT) {            // prefetch tile it+2 into rotating buffer
            const size_t kv = (size_t)(it + 2) * TK;
            unsigned short* Kn = (unsigned short*)(SH + b2);
            unsigned short* Vn = (unsigned short*)(SH + b2 + 8192);
            async_cp16(Kh + kv * HD + kG0, &Kn[dst0]);
            async_cp16(Kh + kv * HD + kG1, &Kn[dst1]);
            async_cp16(Vh + kv + vG0,      &Vn[dst0]);
            async_cp16(Vh + kv + vG1,      &Vn[dst1]);
        }
        const unsigned short* Ks = (const unsigned short*)(SH + b0);
        const unsigned short* Vs = (const unsigned short*)(SH + b0 + 8192);

        // V fragments of tile it (consumed next iteration)
        bf16x8 vfc[2][2];
        #pragma unroll
        for (int dt = 0; dt < 2; ++dt)
            #pragma unroll
            for (int ks = 0; ks < 2; ++ks)
                vfc[dt][ks] = *(const bf16x8*)&Vs[vOffL[dt][ks]];

        // QK MFMAs for tile it (chain on scc)...
        f32x16 scc = (f32x16)(0.f);
        #pragma unroll
        for (int s = 0; s < 4; ++s) {
            bf16x8 kf = *(const bf16x8*)&Ks[kOffL[s]];
            scc = __builtin_amdgcn_mfma_f32_32x32x16_bf16(kf, qf[s], scc, 0, 0, 0);
        }
        // ...overlapped with the independent finish of tile it-1
        FIN(scp, vfp);

        scp = scc;
        #pragma unroll
        for (int dt = 0; dt < 2; ++dt)
            #pragma unroll
            for (int ks = 0; ks < 2; ++ks)
                vfp[dt][ks] = vfc[dt][ks];

        unsigned int btmp = b0; b0 = b1; b1 = b2; b2 = btmp;
    }

    // ---- tail: finish the last tile ----
    FIN(scp, vfp);

    // ---- epilogue: combine nt partials (O and lsum), normalize, store ----
    // ORed overlays buf0; last iter's reads/prefetches touch buf1 only.
    lsum += __shfl_xor(lsum, 32, 64);

    if (nt == 1) {
        if (lane < 32) Lsum[mt * 32 + lane] = lsum;
        #pragma unroll
        for (int dt = 0; dt < 2; ++dt) {
            const int d = dt * 32 + l31;
            #pragma unroll
            for (int g = 0; g < 4; ++g) {
                const int m0 = mt * 32 + 8 * g + 4 * hi;
                const int ph = (m0 >> 2) ^ (d & 15);
                float4 v = { o[dt][4*g+0], o[dt][4*g+1], o[dt][4*g+2], o[dt][4*g+3] };
                *(float4*)&ORed[d * 64 + ph * 4] = v;
            }
        }
    }
    __syncthreads();

    if (nt == 0) {
        float ltot = lsum + Lsum[mt * 32 + l31];
        if (lane < 32) Linv[mt * 32 + lane] = 1.0f / ltot;
        float* Oh = O + ((size_t)bh * SEQ + q0) * HD;
        #pragma unroll
        for (int dt = 0; dt < 2; ++dt) {
            const int d = dt * 32 + l31;
            #pragma unroll
            for (int g = 0; g < 4; ++g) {
                const int m0 = mt * 32 + 8 * g + 4 * hi;
                const int ph = (m0 >> 2) ^ (d & 15);
                float4 part = *(const float4*)&ORed[d * 64 + ph * 4];
                float4 inv4 = *(const float4*)&Linv[m0];
                const float* pp = (const float*)&part;
                const float* ii = (const float*)&inv4;
                #pragma unroll
                for (int j = 0; j < 4; ++j)
                    Oh[(size_t)(m0 + j) * HD + d] = (o[dt][4*g+j] + pp[j]) * ii[j];
            }
        }
    }
}

// ---------------- fallback (no-workspace) kernel ----------------
#define PAD 8
#define LSTR (HD + PAD)

__global__ __launch_bounds__(256)
void fa_fwd_fb(const float* __restrict__ Q, const float* __restrict__ K,
               const float* __restrict__ V, float* __restrict__ O) {
    const int x  = blockIdx.x & 7;
    const int t  = blockIdx.x >> 3;
    const int bh = x + 8 * (t % 3);
    const int qt = t / 3;
    const int q0 = qt * TQ;
    const long base = (long)bh * SEQ * HD;

    __shared__ unsigned short Qs[TQ][LSTR];
    __shared__ unsigned short Ks2[64][LSTR];
    __shared__ unsigned short Vt[HD][64 + PAD];
    __shared__ unsigned short Ps2[4][16][LSTR];

    const int tid  = threadIdx.x;
    const int wave = tid >> 6;
    const int lane = tid & 63;
    const int col  = lane & 15;
    const int quad = lane >> 4;
    const int m0   = wave * 16;

    #pragma unroll
    for (int i = 0; i < 4; ++i) {
        int idx = tid + 256 * i;
        int row = idx >> 4;
        int c4  = (idx & 15) * 4;
        float4 v = *(const float4*)&Q[base + (long)(q0 + row) * HD + c4];
        ushort4 b = { f2bf(v.x), f2bf(v.y), f2bf(v.z), f2bf(v.w) };
        *(ushort4*)&Qs[row][c4] = b;
    }
    __syncthreads();

    bf16x8 aq0 = *(const bf16x8*)&Qs[m0 + col][quad * 8];
    bf16x8 aq1 = *(const bf16x8*)&Qs[m0 + col][32 + quad * 8];

    f32x4 o0 = {0.f,0.f,0.f,0.f}, o1 = o0, o2 = o0, o3 = o0;
    float l[4] = {0.f, 0.f, 0.f, 0.f};
    const float scale = 0.022097086912079608f;

    for (int kv0 = 0; kv0 < SEQ; kv0 += 64) {
        __syncthreads();
        #pragma unroll
        for (int i = 0; i < 4; ++i) {
            int idx = tid + 256 * i;
            int row = idx >> 4;
            int c4  = (idx & 15) * 4;
            float4 kv = *(const float4*)&K[base + (long)(kv0 + row) * HD + c4];
            ushort4 kb = { f2bf(kv.x), f2bf(kv.y), f2bf(kv.z), f2bf(kv.w) };
            *(ushort4*)&Ks2[row][c4] = kb;
            float4 vv = *(const float4*)&V[base + (long)(kv0 + row) * HD + c4];
            Vt[c4 + 0][row] = f2bf(vv.x);
            Vt[c4 + 1][row] = f2bf(vv.y);
            Vt[c4 + 2][row] = f2bf(vv.z);
            Vt[c4 + 3][row] = f2bf(vv.w);
        }
        __syncthreads();

        f32x4 sc[4];
        #pragma unroll
        for (int n = 0; n < 4; ++n) {
            bf16x8 b0 = *(const bf16x8*)&Ks2[n * 16 + col][quad * 8];
            bf16x8 b1 = *(const bf16x8*)&Ks2[n * 16 + col][32 + quad * 8];
            f32x4 acc = {0.f,0.f,0.f,0.f};
            acc = __builtin_amdgcn_mfma_f32_16x16x32_bf16(aq0, b0, acc, 0, 0, 0);
            acc = __builtin_amdgcn_mfma_f32_16x16x32_bf16(aq1, b1, acc, 0, 0, 0);
            sc[n] = acc;
        }

        float tsum[4] = {0.f, 0.f, 0.f, 0.f};
        #pragma unroll
        for (int n = 0; n < 4; ++n) {
            #pragma unroll
            for (int r = 0; r < 4; ++r) {
                float p = __expf(sc[n][r] * scale);
                tsum[r] += p;
                Ps2[wave][quad * 4 + r][n * 16 + col] = f2bf(p);
            }
        }
        #pragma unroll
        for (int off = 1; off < 16; off <<= 1) {
            #pragma unroll
            for (int r = 0; r < 4; ++r) tsum[r] += __shfl_xor(tsum[r], off, 64);
        }
        #pragma unroll
        for (int r = 0; r < 4; ++r) l[r] += tsum[r];

        bf16x8 ap0 = *(const bf16x8*)&Ps2[wave][col][quad * 8];
        bf16x8 ap1 = *(const bf16x8*)&Ps2[wave][col][32 + quad * 8];
        #pragma unroll
        for (int n = 0; n < 4; ++n) {
            bf16x8 b0 = *(const bf16x8*)&Vt[n * 16 + col][quad * 8];
            bf16x8 b1 = *(const bf16x8*)&Vt[n * 16 + col][32 + quad * 8];
            f32x4* op = (n == 0) ? &o0 : (n == 1) ? &o1 : (n == 2) ? &o2 : &o3;
            *op = __builtin_amdgcn_mfma_f32_16x16x32_bf16(ap0, b0, *op, 0, 0, 0);
            *op = __builtin_amdgcn_mfma_f32_16x16x32_bf16(ap1, b1, *op, 0, 0, 0);
        }
    }

    float inv[4];
    #pragma unroll
    for (int r = 0; r < 4; ++r) inv[r] = 1.0f / l[r];
    #pragma unroll
    for (int r = 0; r < 4; ++r) {
        long row = base + (long)(q0 + m0 + quad * 4 + r) * HD;
        O[row +  0 + col] = o0[r] * inv[r];
        O[row + 16 + col] = o1[r] * inv[r];
        O[row + 32 + col] = o2[r] * inv[r];
        O[row + 48 + col] = o3[r] * inv[r];
    }
}

extern "C" void kernel_launch(void* const* d_in, const int* in_sizes, int n_in,
                              void* d_out, int out_size, void* d_ws, size_t ws_size,
                              hipStream_t stream) {
    const float* Q = (const float*)d_in[0];
    const float* K = (const float*)d_in[1];
    const float* V = (const float*)d_in[2];
    float* O = (float*)d_out;

    const size_t tensorElems = (size_t)NHEADS * SEQ * HD;
    const size_t need = 2 * tensorElems * sizeof(unsigned short) + 64;

    if (ws_size >= need) {
        unsigned short* Kb  = (unsigned short*)d_ws;
        unsigned short* Vtb = Kb + tensorElems;
        unsigned int* cnt   = (unsigned int*)(Vtb + tensorElems);
        hipMemsetAsync(cnt, 0, sizeof(unsigned int), stream);
        const float qs = (float)(1.4426950408889634 / sqrt(2048.0));  // log2e/sqrt(S)
        fa_all<<<dim3(NBLK), dim3(256), 0, stream>>>(Q, K, V, Kb, Vtb, cnt, O, qs);
    } else {
        fa_fwd_fb<<<dim3(NHEADS * (SEQ / TQ)), dim3(256), 0, stream>>>(Q, K, V, O);
    }
}

// Round 5
// 168.685 us; speedup vs baseline: 1.2832x; 1.2832x over previous
//
#include <hip/hip_runtime.h>
#include <hip/hip_bf16.h>
#include <math.h>
#include <stdint.h>

#define BATCH 2
#define NH 12
#define SEQ 2048
#define HD 64
#define TQ 64
#define TK 64
#define NHEADS (BATCH*NH)
#define NIT (SEQ / TK)

typedef short bf16x8 __attribute__((ext_vector_type(8)));
typedef float f32x4 __attribute__((ext_vector_type(4)));
typedef float f32x16 __attribute__((ext_vector_type(16)));
typedef unsigned short us4_t __attribute__((ext_vector_type(4)));
typedef unsigned short us8_t __attribute__((ext_vector_type(8)));
typedef unsigned int u32x4 __attribute__((ext_vector_type(4)));

#if __has_builtin(__builtin_amdgcn_exp2f)
#define EXP2F(x) __builtin_amdgcn_exp2f(x)
#else
#define EXP2F(x) exp2f(x)
#endif

static __device__ __forceinline__ unsigned short f2bf(float f) {
    unsigned int u = __float_as_uint(f);
    u += 0x7fffu + ((u >> 16) & 1u);   // RTNE
    return (unsigned short)(u >> 16);
}

static __device__ __forceinline__ unsigned int pack2bf(float a, float b) {
    __hip_bfloat162 v = __float22bfloat162_rn(float2{a, b});
    return *(unsigned int*)&v;          // low short = a
}

// Conflict-free 64x64-bf16 tile layout (Q staging only): 32 row-pairs x 256B,
// 16 positions of 16B, pos = ((r&1)*8 | c) ^ ((r>>1)&15).
static __device__ __forceinline__ int tile_off(int r, int c) {   // shorts, c 0..7
    int rp  = r >> 1;
    int pos = (((r & 1) << 3) | c) ^ (rp & 15);
    return rp * 128 + pos * 8;
}

// ---- pre-pass: K -> bf16 (dense), V -> bf16 transposed [bh][d][s'] where
// s' = s with bits 2<->3 swapped inside each 32-block (pi-permutation that
// makes the S^T C-layout register order equal the PV A-operand order).
__global__ __launch_bounds__(256)
void prep_kv(const float* __restrict__ K, const float* __restrict__ V,
             unsigned short* __restrict__ Kb, unsigned short* __restrict__ Vtb) {
    __shared__ unsigned short T[64][66];
    const int bh = blockIdx.x >> 5;
    const int s0 = (blockIdx.x & 31) * 64;
    const int tid = threadIdx.x;
    const size_t off = ((size_t)bh * SEQ + s0) * HD;

    #pragma unroll
    for (int u = 0; u < 4; ++u) {                 // K: dense 16B loads, 8B stores
        int idx = u * 1024 + tid * 4;
        float4 a = *(const float4*)&K[off + idx];
        us4_t r4 = { f2bf(a.x), f2bf(a.y), f2bf(a.z), f2bf(a.w) };
        *(us4_t*)&Kb[off + idx] = r4;
    }
    #pragma unroll
    for (int u = 0; u < 4; ++u) {                 // V: dense loads -> padded LDS
        int idx = u * 1024 + tid * 4;
        int r = idx >> 6, col = idx & 63;
        float4 a = *(const float4*)&V[off + idx];
        *(unsigned int*)&T[r][col]     = pack2bf(a.x, a.y);
        *(unsigned int*)&T[r][col + 2] = pack2bf(a.z, a.w);
    }
    __syncthreads();
    unsigned short* Vdst = Vtb + (size_t)bh * HD * SEQ;
    const int g = tid & 7, dd = tid >> 3;         // dd 0..31
    #pragma unroll
    for (int h = 0; h < 2; ++h) {
        int d = dd + 32 * h;
        us8_t r8;
        #pragma unroll
        for (int j = 0; j < 8; ++j) {
            // pi: swap bits 2,3 of the 64-local column index (g*8 + j)
            int src = ((g >> 1) << 4) + ((j >> 2) << 3) + ((g & 1) << 2) + (j & 3);
            r8[j] = T[src][d];
        }
        *(us8_t*)&Vdst[(size_t)d * SEQ + s0 + g * 8] = r8;
    }
}

// ---------------- main flash-attention kernel (32x32x16 MFMA) ----------------
// R11: barrier-free main loop with direct L2->register K/V loads.
// R8/R9 evidence: ~3000 cyc/iter vs ~900 cyc issue work, with MfmaUtil 22% /
// VALUBusy 42% and no pipe saturated -> the 4-wave barrier lockstep (every
// iter: lgkmcnt(0)+vmcnt(N)+s_barrier, all waves pay max jitter x32) is the
// remaining structural stall. K/V per head is only 512 KB bf16, shared by 32
// co-resident blocks -> L2-hot (Common-mistake #7 / m169: staging L2-fit data
// is pure overhead). The old LDS fragments are bit-identical to contiguous
// 16B slices of Kb/Vtb, so each wave loads its MFMA fragments directly from
// global into registers: no global_load_lds, no in-loop ds_read, NO in-loop
// barriers. Waves run independently (m191 setprio-positive regime); the
// compiler's automatic vmcnt(8) before first use of prefetched regs gives a
// full iteration of load-latency cover. Identical arithmetic -> same absmax.
__global__ __launch_bounds__(256, 3)
void fa_main(const float* __restrict__ Q,
             const unsigned short* __restrict__ Kb,
             const unsigned short* __restrict__ Vtb,
             float* __restrict__ O, float qs) {
    const int x  = blockIdx.x & 7;
    const int t  = blockIdx.x >> 3;
    const int bh = x + 8 * (t % 3);
    const int qt = t / 3;
    const int q0 = qt * TQ;

    // LDS: Q staging (8 KB) overlaid by epilogue ORed (16 KB) + Lsum/Linv
    __shared__ __align__(16) unsigned char SH[16896];
    unsigned short* QS = (unsigned short*)SH;              // prologue only
    float* ORed = (float*)SH;                              // 64x64 f32 (epilogue)
    float* Lsum = (float*)(SH + 16384);                    // 64 f32
    float* Linv = (float*)(SH + 16640);                    // 64 f32

    const int tid  = threadIdx.x;
    const int w    = tid >> 6;
    const int mt   = w >> 1;
    const int nt   = w & 1;
    const int lane = tid & 63;
    const int l31  = lane & 31;
    const int hi   = lane >> 5;

    const float*          Qh = Q   + ((size_t)bh * SEQ + q0) * HD;
    const unsigned short* Kh = Kb  + (size_t)bh * SEQ * HD;
    const unsigned short* Vh = Vtb + (size_t)bh * HD * SEQ;

    // ---- prologue: Q (fp32 -> scaled bf16) -> QS; extract B-fragments ----
    #pragma unroll
    for (int u = 0; u < 4; ++u) {
        int idx = u * 1024 + tid * 4;
        int r = idx >> 6, col = idx & 63;
        float4 a = *(const float4*)&Qh[idx];
        uint2 pk = { pack2bf(a.x * qs, a.y * qs), pack2bf(a.z * qs, a.w * qs) };
        *(uint2*)&QS[tile_off(r, col >> 3) + (col & 7)] = pk;
    }
    __syncthreads();   // QS complete
    bf16x8 qf[4];
    #pragma unroll
    for (int s = 0; s < 4; ++s)
        qf[s] = *(const bf16x8*)&QS[tile_off(mt * 32 + l31, s * 2 + hi)];
    __syncthreads();   // all waves extracted qf; ORed overlay safe after this

    // ---- per-lane global fragment pointers (bit-identical to old LDS frags):
    //  kf[s]      = Kh[(kv + nt*32+l31)*HD + (s*2+hi)*8]       (s imm +32B)
    //  vf[dt][ks] = Vh[(dt*32+l31)*SEQ + kv + (nt*4+ks*2+hi)*8] (ks imm +32B)
    const unsigned short* kP  = Kh + (size_t)(nt * 32 + l31) * HD + hi * 8;
    const unsigned short* vP0 = Vh + (size_t)(l31) * SEQ        + (nt * 4 + hi) * 8;
    const unsigned short* vP1 = Vh + (size_t)(32 + l31) * SEQ   + (nt * 4 + hi) * 8;

    bf16x8 kc[4], vc[2][2], kn[4], vn[2][2];
    // tile 0 fragments
    #pragma unroll
    for (int s = 0; s < 4; ++s) kc[s] = *(const bf16x8*)(kP + s * 16);
    vc[0][0] = *(const bf16x8*)(vP0);
    vc[0][1] = *(const bf16x8*)(vP0 + 16);
    vc[1][0] = *(const bf16x8*)(vP1);
    vc[1][1] = *(const bf16x8*)(vP1 + 16);
    const unsigned short* kPn  = kP  + (size_t)TK * HD;
    const unsigned short* vP0n = vP0 + TK;
    const unsigned short* vP1n = vP1 + TK;

    f32x16 o[2];
    o[0] = (f32x16)(0.f);
    o[1] = (f32x16)(0.f);
    float lsum = 0.f;

    #pragma unroll 2
    for (int it = 0; it < NIT; ++it) {
        // ---- prefetch tile it+1 fragments into registers (1-iter cover) ----
        if (it + 1 < NIT) {
            #pragma unroll
            for (int s = 0; s < 4; ++s) kn[s] = *(const bf16x8*)(kPn + s * 16);
            vn[0][0] = *(const bf16x8*)(vP0n);
            vn[0][1] = *(const bf16x8*)(vP0n + 16);
            vn[1][0] = *(const bf16x8*)(vP1n);
            vn[1][1] = *(const bf16x8*)(vP1n + 16);
            kPn  += (size_t)TK * HD;
            vP0n += TK;
            vP1n += TK;
        }

        // ---- S^T quadrant = K(32x64) . Q^T(64x32): 4 MFMAs ----
        f32x16 sc = (f32x16)(0.f);
        __builtin_amdgcn_s_setprio(1);
        #pragma unroll
        for (int s = 0; s < 4; ++s)
            sc = __builtin_amdgcn_mfma_f32_32x32x16_bf16(kc[s], qf[s], sc, 0, 0, 0);
        __builtin_amdgcn_s_setprio(0);

        // ---- half 0: exp2 + pack + PV ks=0 ----
        float e0[8], e1[8];
        #pragma unroll
        for (int r = 0; r < 8; ++r) e0[r] = EXP2F(sc[r]);
        union { u32x4 d; bf16x8 h; } pu0, pu1;
        pu0.d = (u32x4){ pack2bf(e0[0], e0[1]), pack2bf(e0[2], e0[3]),
                         pack2bf(e0[4], e0[5]), pack2bf(e0[6], e0[7]) };
        bf16x8 pf0 = pu0.h;
        __builtin_amdgcn_s_setprio(1);
        o[0] = __builtin_amdgcn_mfma_f32_32x32x16_bf16(pf0, vc[0][0], o[0], 0, 0, 0);
        o[1] = __builtin_amdgcn_mfma_f32_32x32x16_bf16(pf0, vc[1][0], o[1], 0, 0, 0);
        __builtin_amdgcn_s_setprio(0);

        // ---- half 1: exp2 + pack + PV ks=1 ----
        #pragma unroll
        for (int r = 0; r < 8; ++r) e1[r] = EXP2F(sc[8 + r]);
        pu1.d = (u32x4){ pack2bf(e1[0], e1[1]), pack2bf(e1[2], e1[3]),
                         pack2bf(e1[4], e1[5]), pack2bf(e1[6], e1[7]) };
        bf16x8 pf1 = pu1.h;
        __builtin_amdgcn_s_setprio(1);
        o[0] = __builtin_amdgcn_mfma_f32_32x32x16_bf16(pf1, vc[0][1], o[0], 0, 0, 0);
        o[1] = __builtin_amdgcn_mfma_f32_32x32x16_bf16(pf1, vc[1][1], o[1], 0, 0, 0);
        __builtin_amdgcn_s_setprio(0);

        // ---- lsum: pairwise tree ----
        float t0 = ((e0[0] + e0[1]) + (e0[2] + e0[3]))
                 + ((e0[4] + e0[5]) + (e0[6] + e0[7]));
        float t1 = ((e1[0] + e1[1]) + (e1[2] + e1[3]))
                 + ((e1[4] + e1[5]) + (e1[6] + e1[7]));
        lsum += t0 + t1;

        // ---- rotate register tiles (renamed away under unroll 2) ----
        #pragma unroll
        for (int s = 0; s < 4; ++s) kc[s] = kn[s];
        #pragma unroll
        for (int dt = 0; dt < 2; ++dt)
            #pragma unroll
            for (int ks = 0; ks < 2; ++ks)
                vc[dt][ks] = vn[dt][ks];
    }

    // ---- epilogue: combine nt partials (O and lsum), normalize, store ----
    lsum += __shfl_xor(lsum, 32, 64);

    if (nt == 1) {
        if (lane < 32) Lsum[mt * 32 + lane] = lsum;
        #pragma unroll
        for (int dt = 0; dt < 2; ++dt) {
            const int d = dt * 32 + l31;
            #pragma unroll
            for (int g = 0; g < 4; ++g) {
                const int m0 = mt * 32 + 8 * g + 4 * hi;
                const int ph = (m0 >> 2) ^ (d & 15);
                float4 v = { o[dt][4*g+0], o[dt][4*g+1], o[dt][4*g+2], o[dt][4*g+3] };
                *(float4*)&ORed[d * 64 + ph * 4] = v;
            }
        }
    }
    __syncthreads();

    if (nt == 0) {
        float ltot = lsum + Lsum[mt * 32 + l31];
        if (lane < 32) Linv[mt * 32 + lane] = 1.0f / ltot;
        float* Oh = O + ((size_t)bh * SEQ + q0) * HD;
        #pragma unroll
        for (int dt = 0; dt < 2; ++dt) {
            const int d = dt * 32 + l31;
            #pragma unroll
            for (int g = 0; g < 4; ++g) {
                const int m0 = mt * 32 + 8 * g + 4 * hi;
                const int ph = (m0 >> 2) ^ (d & 15);
                float4 part = *(const float4*)&ORed[d * 64 + ph * 4];
                float4 inv4 = *(const float4*)&Linv[m0];
                const float* pp = (const float*)&part;
                const float* ii = (const float*)&inv4;
                #pragma unroll
                for (int j = 0; j < 4; ++j)
                    Oh[(size_t)(m0 + j) * HD + d] = (o[dt][4*g+j] + pp[j]) * ii[j];
            }
        }
    }
}

// ---------------- fallback (no-workspace) kernel ----------------
#define PAD 8
#define LSTR (HD + PAD)

__global__ __launch_bounds__(256)
void fa_fwd_fb(const float* __restrict__ Q, const float* __restrict__ K,
               const float* __restrict__ V, float* __restrict__ O) {
    const int x  = blockIdx.x & 7;
    const int t  = blockIdx.x >> 3;
    const int bh = x + 8 * (t % 3);
    const int qt = t / 3;
    const int q0 = qt * TQ;
    const long base = (long)bh * SEQ * HD;

    __shared__ unsigned short Qs[TQ][LSTR];
    __shared__ unsigned short Ks2[64][LSTR];
    __shared__ unsigned short Vt[HD][64 + PAD];
    __shared__ unsigned short Ps2[4][16][LSTR];

    const int tid  = threadIdx.x;
    const int wave = tid >> 6;
    const int lane = tid & 63;
    const int col  = lane & 15;
    const int quad = lane >> 4;
    const int m0   = wave * 16;

    #pragma unroll
    for (int i = 0; i < 4; ++i) {
        int idx = tid + 256 * i;
        int row = idx >> 4;
        int c4  = (idx & 15) * 4;
        float4 v = *(const float4*)&Q[base + (long)(q0 + row) * HD + c4];
        ushort4 b = { f2bf(v.x), f2bf(v.y), f2bf(v.z), f2bf(v.w) };
        *(ushort4*)&Qs[row][c4] = b;
    }
    __syncthreads();

    bf16x8 aq0 = *(const bf16x8*)&Qs[m0 + col][quad * 8];
    bf16x8 aq1 = *(const bf16x8*)&Qs[m0 + col][32 + quad * 8];

    f32x4 o0 = {0.f,0.f,0.f,0.f}, o1 = o0, o2 = o0, o3 = o0;
    float l[4] = {0.f, 0.f, 0.f, 0.f};
    const float scale = 0.022097086912079608f;

    for (int kv0 = 0; kv0 < SEQ; kv0 += 64) {
        __syncthreads();
        #pragma unroll
        for (int i = 0; i < 4; ++i) {
            int idx = tid + 256 * i;
            int row = idx >> 4;
            int c4  = (idx & 15) * 4;
            float4 kv = *(const float4*)&K[base + (long)(kv0 + row) * HD + c4];
            ushort4 kb = { f2bf(kv.x), f2bf(kv.y), f2bf(kv.z), f2bf(kv.w) };
            *(ushort4*)&Ks2[row][c4] = kb;
            float4 vv = *(const float4*)&V[base + (long)(kv0 + row) * HD + c4];
            Vt[c4 + 0][row] = f2bf(vv.x);
            Vt[c4 + 1][row] = f2bf(vv.y);
            Vt[c4 + 2][row] = f2bf(vv.z);
            Vt[c4 + 3][row] = f2bf(vv.w);
        }
        __syncthreads();

        f32x4 sc[4];
        #pragma unroll
        for (int n = 0; n < 4; ++n) {
            bf16x8 b0 = *(const bf16x8*)&Ks2[n * 16 + col][quad * 8];
            bf16x8 b1 = *(const bf16x8*)&Ks2[n * 16 + col][32 + quad * 8];
            f32x4 acc = {0.f,0.f,0.f,0.f};
            acc = __builtin_amdgcn_mfma_f32_16x16x32_bf16(aq0, b0, acc, 0, 0, 0);
            acc = __builtin_amdgcn_mfma_f32_16x16x32_bf16(aq1, b1, acc, 0, 0, 0);
            sc[n] = acc;
        }

        float tsum[4] = {0.f, 0.f, 0.f, 0.f};
        #pragma unroll
        for (int n = 0; n < 4; ++n) {
            #pragma unroll
            for (int r = 0; r < 4; ++r) {
                float p = __expf(sc[n][r] * scale);
                tsum[r] += p;
                Ps2[wave][quad * 4 + r][n * 16 + col] = f2bf(p);
            }
        }
        #pragma unroll
        for (int off = 1; off < 16; off <<= 1) {
            #pragma unroll
            for (int r = 0; r < 4; ++r) tsum[r] += __shfl_xor(tsum[r], off, 64);
        }
        #pragma unroll
        for (int r = 0; r < 4; ++r) l[r] += tsum[r];

        bf16x8 ap0 = *(const bf16x8*)&Ps2[wave][col][quad * 8];
        bf16x8 ap1 = *(const bf16x8*)&Ps2[wave][col][32 + quad * 8];
        #pragma unroll
        for (int n = 0; n < 4; ++n) {
            bf16x8 b0 = *(const bf16x8*)&Vt[n * 16 + col][quad * 8];
            bf16x8 b1 = *(const bf16x8*)&Vt[n * 16 + col][32 + quad * 8];
            f32x4* op = (n == 0) ? &o0 : (n == 1) ? &o1 : (n == 2) ? &o2 : &o3;
            *op = __builtin_amdgcn_mfma_f32_16x16x32_bf16(ap0, b0, *op, 0, 0, 0);
            *op = __builtin_amdgcn_mfma_f32_16x16x32_bf16(ap1, b1, *op, 0, 0, 0);
        }
    }

    float inv[4];
    #pragma unroll
    for (int r = 0; r < 4; ++r) inv[r] = 1.0f / l[r];
    #pragma unroll
    for (int r = 0; r < 4; ++r) {
        long row = base + (long)(q0 + m0 + quad * 4 + r) * HD;
        O[row +  0 + col] = o0[r] * inv[r];
        O[row + 16 + col] = o1[r] * inv[r];
        O[row + 32 + col] = o2[r] * inv[r];
        O[row + 48 + col] = o3[r] * inv[r];
    }
}

extern "C" void kernel_launch(void* const* d_in, const int* in_sizes, int n_in,
                              void* d_out, int out_size, void* d_ws, size_t ws_size,
                              hipStream_t stream) {
    const float* Q = (const float*)d_in[0];
    const float* K = (const float*)d_in[1];
    const float* V = (const float*)d_in[2];
    float* O = (float*)d_out;

    const size_t tensorElems = (size_t)NHEADS * SEQ * HD;
    const size_t need = 2 * tensorElems * sizeof(unsigned short);

    if (ws_size >= need) {
        unsigned short* Kb  = (unsigned short*)d_ws;
        unsigned short* Vtb = Kb + tensorElems;
        const float qs = (float)(1.4426950408889634 / sqrt(2048.0));  // log2e/sqrt(S)
        prep_kv<<<dim3(NHEADS * (SEQ / 64)), dim3(256), 0, stream>>>(K, V, Kb, Vtb);
        fa_main<<<dim3(NHEADS * (SEQ / TQ)), dim3(256), 0, stream>>>(Q, Kb, Vtb, O, qs);
    } else {
        fa_fwd_fb<<<dim3(NHEADS * (SEQ / TQ)), dim3(256), 0, stream>>>(Q, K, V, O);
    }
}

// Round 6
// 117.411 us; speedup vs baseline: 1.8436x; 1.4367x over previous
//
#include <hip/hip_runtime.h>
#include <hip/hip_bf16.h>
#include <math.h>
#include <stdint.h>

#define BATCH 2
#define NH 12
#define SEQ 2048
#define HD 64
#define TQ 64
#define TK 64
#define NHEADS (BATCH*NH)
#define NIT (SEQ / TK)

typedef short bf16x8 __attribute__((ext_vector_type(8)));
typedef float f32x4 __attribute__((ext_vector_type(4)));
typedef float f32x16 __attribute__((ext_vector_type(16)));
typedef unsigned short us4_t __attribute__((ext_vector_type(4)));
typedef unsigned short us8_t __attribute__((ext_vector_type(8)));
typedef unsigned int u32x4 __attribute__((ext_vector_type(4)));

#if __has_builtin(__builtin_amdgcn_exp2f)
#define EXP2F(x) __builtin_amdgcn_exp2f(x)
#else
#define EXP2F(x) exp2f(x)
#endif

static __device__ __forceinline__ unsigned short f2bf(float f) {
    unsigned int u = __float_as_uint(f);
    u += 0x7fffu + ((u >> 16) & 1u);   // RTNE
    return (unsigned short)(u >> 16);
}

static __device__ __forceinline__ unsigned int pack2bf(float a, float b) {
    __hip_bfloat162 v = __float22bfloat162_rn(float2{a, b});
    return *(unsigned int*)&v;          // low short = a
}

static __device__ __forceinline__ void async_cp16(const void* g, void* l) {
    __builtin_amdgcn_global_load_lds(
        (const __attribute__((address_space(1))) void*)g,
        (__attribute__((address_space(3))) void*)(uintptr_t)l,
        16, 0, 0);
}

// Conflict-free 64x64-bf16 tile layout: 32 row-pairs x 256B, 16 positions of
// 16B, pos = ((r&1)*8 | c) ^ ((r>>1)&15).
static __device__ __forceinline__ int tile_off(int r, int c) {   // shorts, c 0..7
    int rp  = r >> 1;
    int pos = (((r & 1) << 3) | c) ^ (rp & 15);
    return rp * 128 + pos * 8;
}

// ---- pre-pass: K -> bf16 (dense), V -> bf16 transposed [bh][d][s'] where
// s' = s with bits 2<->3 swapped inside each 32-block (pi-permutation that
// makes the S^T C-layout register order equal the PV A-operand order).
__global__ __launch_bounds__(256)
void prep_kv(const float* __restrict__ K, const float* __restrict__ V,
             unsigned short* __restrict__ Kb, unsigned short* __restrict__ Vtb) {
    __shared__ unsigned short T[64][66];
    const int bh = blockIdx.x >> 5;
    const int s0 = (blockIdx.x & 31) * 64;
    const int tid = threadIdx.x;
    const size_t off = ((size_t)bh * SEQ + s0) * HD;

    #pragma unroll
    for (int u = 0; u < 4; ++u) {                 // K: dense 16B loads, 8B stores
        int idx = u * 1024 + tid * 4;
        float4 a = *(const float4*)&K[off + idx];
        us4_t r4 = { f2bf(a.x), f2bf(a.y), f2bf(a.z), f2bf(a.w) };
        *(us4_t*)&Kb[off + idx] = r4;
    }
    #pragma unroll
    for (int u = 0; u < 4; ++u) {                 // V: dense loads -> padded LDS
        int idx = u * 1024 + tid * 4;
        int r = idx >> 6, col = idx & 63;
        float4 a = *(const float4*)&V[off + idx];
        *(unsigned int*)&T[r][col]     = pack2bf(a.x, a.y);
        *(unsigned int*)&T[r][col + 2] = pack2bf(a.z, a.w);
    }
    __syncthreads();
    unsigned short* Vdst = Vtb + (size_t)bh * HD * SEQ;
    const int g = tid & 7, dd = tid >> 3;         // dd 0..31
    #pragma unroll
    for (int h = 0; h < 2; ++h) {
        int d = dd + 32 * h;
        us8_t r8;
        #pragma unroll
        for (int j = 0; j < 8; ++j) {
            // pi: swap bits 2,3 of the 64-local column index (g*8 + j)
            int src = ((g >> 1) << 4) + ((j >> 2) << 3) + ((g & 1) << 2) + (j & 3);
            r8[j] = T[src][d];
        }
        *(us8_t*)&Vdst[(size_t)d * SEQ + s0 + g * 8] = r8;
    }
}

// ---------------- main flash-attention kernel (32x32x16 MFMA) ----------------
// R12 = R9's deferred-PV pipeline (only fa_main change that measurably helped,
// ~+12%) on R0's minimal 33,280-byte DOUBLE-buffer layout (best residency:
// 4 blocks/CU capacity vs grid's 3, robust to LDS allocation granularity —
// occupancy counters at 49.6KB suggested only ~2 blocks/CU resident).
// R11 lesson: keep global_load_lds staging — it converts the 128B/4KB-stride
// fragment gathers into dense coalesced loads; direct L2->reg was 2.4x slower.
// Schedule per iter t (tile t in buf[t&1]):
//   lgkmcnt(0); vmcnt(0); s_barrier        // my reads done; own cps retired
//   prefetch tile t+1 -> buf[1-(t&1)]      // overwrites t-1's buffer: its last
//                                          // reads completed before this barrier
//   ds_read vfc + QK(t)  ||  FIN(t-1)      // exp/PV of t-1 fills QK's shadow
// R8 measured drain-vs-counted vmcnt neutral, so the dbuf drain costs nothing.
__global__ __launch_bounds__(256, 3)
void fa_main(const float* __restrict__ Q,
             const unsigned short* __restrict__ Kb,
             const unsigned short* __restrict__ Vtb,
             float* __restrict__ O, float qs) {
    const int x  = blockIdx.x & 7;
    const int t  = blockIdx.x >> 3;
    const int bh = x + 8 * (t % 3);
    const int qt = t / 3;
    const int q0 = qt * TQ;

    __shared__ __align__(16) unsigned char SH[33280];
    // buf0: K@0, V@8192 ; buf1: K@16384, V@24576 ; QS overlays buf1-V
    unsigned short* QS = (unsigned short*)(SH + 24576);
    float* Lsum = (float*)(SH + 32768);                    // 64 f32
    float* Linv = (float*)(SH + 33024);                    // 64 f32
    float* ORed = (float*)SH;                              // 64x64 f32 (buf0 overlay)

    const int tid  = threadIdx.x;
    const int w    = tid >> 6;
    const int mt   = w >> 1;
    const int nt   = w & 1;
    const int lane = tid & 63;
    const int l31  = lane & 31;
    const int hi   = lane >> 5;

    const float*          Qh = Q   + ((size_t)bh * SEQ + q0) * HD;
    const unsigned short* Kh = Kb  + (size_t)bh * SEQ * HD;
    const unsigned short* Vh = Vtb + (size_t)bh * HD * SEQ;

    // ---- per-lane staging source offsets (loop-invariant) ----
    int rS[2], cS[2];
    #pragma unroll
    for (int i = 0; i < 2; ++i) {
        int rp = w * 8 + 4 * i + (lane >> 4);
        int lc = (lane & 15) ^ (rp & 15);
        rS[i] = 2 * rp + (lc >> 3);
        cS[i] = lc & 7;
    }
    const int dst0 = (w * 8 + 0) * 128, dst1 = (w * 8 + 4) * 128;  // shorts
    const size_t kG0 = (size_t)rS[0] * HD  + cS[0] * 8;
    const size_t kG1 = (size_t)rS[1] * HD  + cS[1] * 8;
    const size_t vG0 = (size_t)rS[0] * SEQ + cS[0] * 8;
    const size_t vG1 = (size_t)rS[1] * SEQ + cS[1] * 8;

    // ---- prologue: tile 0 -> buf0 (async); Q (fp32 -> scaled bf16) -> QS ----
    {
        unsigned short* K0 = (unsigned short*)(SH);
        unsigned short* V0 = (unsigned short*)(SH + 8192);
        async_cp16(Kh + kG0, &K0[dst0]);
        async_cp16(Kh + kG1, &K0[dst1]);
        async_cp16(Vh + vG0, &V0[dst0]);
        async_cp16(Vh + vG1, &V0[dst1]);
    }
    #pragma unroll
    for (int u = 0; u < 4; ++u) {
        int idx = u * 1024 + tid * 4;
        int r = idx >> 6, col = idx & 63;
        float4 a = *(const float4*)&Qh[idx];
        uint2 pk = { pack2bf(a.x * qs, a.y * qs), pack2bf(a.z * qs, a.w * qs) };
        *(uint2*)&QS[tile_off(r, col >> 3) + (col & 7)] = pk;
    }
    __syncthreads();   // Q staged + tile 0 resident (full drain; prologue only)

    // ---- Q B-fragments (rows mt*32..+32) -> registers; then QS is free ----
    bf16x8 qf[4];
    #pragma unroll
    for (int s = 0; s < 4; ++s)
        qf[s] = *(const bf16x8*)&QS[tile_off(mt * 32 + l31, s * 2 + hi)];
    __syncthreads();   // everyone extracted Q; buf1 may be overwritten now

    // ---- tile 1 -> buf1 (in flight across peel iter 0's compute) ----
    {
        unsigned short* K1 = (unsigned short*)(SH + 16384);
        unsigned short* V1 = (unsigned short*)(SH + 24576);
        async_cp16(Kh + (size_t)TK * HD + kG0, &K1[dst0]);
        async_cp16(Kh + (size_t)TK * HD + kG1, &K1[dst1]);
        async_cp16(Vh + (size_t)TK + vG0,      &V1[dst0]);
        async_cp16(Vh + (size_t)TK + vG1,      &V1[dst1]);
    }

    // ---- hoisted fragment LDS offsets ----
    int kOffL[4], vOffL[2][2];
    #pragma unroll
    for (int s = 0; s < 4; ++s) kOffL[s] = tile_off(nt * 32 + l31, s * 2 + hi);
    #pragma unroll
    for (int dt = 0; dt < 2; ++dt)
        #pragma unroll
        for (int ks = 0; ks < 2; ++ks)
            vOffL[dt][ks] = tile_off(dt * 32 + l31, nt * 4 + ks * 2 + hi);

    f32x16 o[2];
    o[0] = (f32x16)(0.f);
    o[1] = (f32x16)(0.f);
    float lsum = 0.f;

    // deferred finish of a tile: exp2 + pack + PV + lsum (all register-local)
    auto FIN = [&](const f32x16& sp, const bf16x8 (&vp)[2][2]) {
        float e0[8], e1[8];
        #pragma unroll
        for (int r = 0; r < 8; ++r) e0[r] = EXP2F(sp[r]);
        #pragma unroll
        for (int r = 0; r < 8; ++r) e1[r] = EXP2F(sp[8 + r]);
        union { u32x4 d; bf16x8 h; } pu0, pu1;
        pu0.d = (u32x4){ pack2bf(e0[0], e0[1]), pack2bf(e0[2], e0[3]),
                         pack2bf(e0[4], e0[5]), pack2bf(e0[6], e0[7]) };
        pu1.d = (u32x4){ pack2bf(e1[0], e1[1]), pack2bf(e1[2], e1[3]),
                         pack2bf(e1[4], e1[5]), pack2bf(e1[6], e1[7]) };
        bf16x8 pf0 = pu0.h, pf1 = pu1.h;
        o[0] = __builtin_amdgcn_mfma_f32_32x32x16_bf16(pf0, vp[0][0], o[0], 0, 0, 0);
        o[1] = __builtin_amdgcn_mfma_f32_32x32x16_bf16(pf0, vp[1][0], o[1], 0, 0, 0);
        o[0] = __builtin_amdgcn_mfma_f32_32x32x16_bf16(pf1, vp[0][1], o[0], 0, 0, 0);
        o[1] = __builtin_amdgcn_mfma_f32_32x32x16_bf16(pf1, vp[1][1], o[1], 0, 0, 0);
        float t0 = ((e0[0] + e0[1]) + (e0[2] + e0[3]))
                 + ((e0[4] + e0[5]) + (e0[6] + e0[7]));
        float t1 = ((e1[0] + e1[1]) + (e1[2] + e1[3]))
                 + ((e1[4] + e1[5]) + (e1[6] + e1[7]));
        lsum += t0 + t1;
    };

    // pipeline state: scores + V fragments of the previous tile
    f32x16 scp;
    bf16x8 vfp[2][2];

    // ---- peeled iteration 0: tile 0 resident (prologue sync) ----
    {
        const unsigned short* Ks = (const unsigned short*)(SH);
        const unsigned short* Vs = (const unsigned short*)(SH + 8192);
        #pragma unroll
        for (int dt = 0; dt < 2; ++dt)
            #pragma unroll
            for (int ks = 0; ks < 2; ++ks)
                vfp[dt][ks] = *(const bf16x8*)&Vs[vOffL[dt][ks]];
        f32x16 sc = (f32x16)(0.f);
        #pragma unroll
        for (int s = 0; s < 4; ++s) {
            bf16x8 kf = *(const bf16x8*)&Ks[kOffL[s]];
            sc = __builtin_amdgcn_mfma_f32_32x32x16_bf16(kf, qf[s], sc, 0, 0, 0);
        }
        scp = sc;
    }

    // ---- main loop: iter t computes QK(t) and finishes tile t-1 ----
    #pragma unroll 2
    for (int it = 1; it < NIT; ++it) {
        const int cur = it & 1;
        // my ds_reads (incl. deferred V frags) and own cps done before barrier
        asm volatile("s_waitcnt lgkmcnt(0)" ::: "memory");
        asm volatile("s_waitcnt vmcnt(0)" ::: "memory");
        __builtin_amdgcn_s_barrier();   // all waves: tile it resident

        if (it + 1 < NIT) {            // prefetch tile it+1 into other buffer
            const size_t kv = (size_t)(it + 1) * TK;
            unsigned short* Kn = (unsigned short*)(SH + (cur ? 0 : 16384));
            unsigned short* Vn = (unsigned short*)(SH + (cur ? 8192 : 24576));
            async_cp16(Kh + kv * HD + kG0, &Kn[dst0]);
            async_cp16(Kh + kv * HD + kG1, &Kn[dst1]);
            async_cp16(Vh + kv + vG0,      &Vn[dst0]);
            async_cp16(Vh + kv + vG1,      &Vn[dst1]);
        }
        const unsigned short* Ks = (const unsigned short*)(SH + (cur ? 16384 : 0));
        const unsigned short* Vs = (const unsigned short*)(SH + (cur ? 24576 : 8192));

        // V fragments of tile it (consumed next iteration)
        bf16x8 vfc[2][2];
        #pragma unroll
        for (int dt = 0; dt < 2; ++dt)
            #pragma unroll
            for (int ks = 0; ks < 2; ++ks)
                vfc[dt][ks] = *(const bf16x8*)&Vs[vOffL[dt][ks]];

        // QK MFMAs for tile it (chain on scc)...
        f32x16 scc = (f32x16)(0.f);
        #pragma unroll
        for (int s = 0; s < 4; ++s) {
            bf16x8 kf = *(const bf16x8*)&Ks[kOffL[s]];
            scc = __builtin_amdgcn_mfma_f32_32x32x16_bf16(kf, qf[s], scc, 0, 0, 0);
        }
        // ...overlapped with the independent finish of tile it-1
        FIN(scp, vfp);

        scp = scc;
        #pragma unroll
        for (int dt = 0; dt < 2; ++dt)
            #pragma unroll
            for (int ks = 0; ks < 2; ++ks)
                vfp[dt][ks] = vfc[dt][ks];
    }

    // ---- tail: finish the last tile ----
    FIN(scp, vfp);

    // ---- epilogue: combine nt partials (O and lsum), normalize, store ----
    // ORed overlays buf0. Last tile (31) lives in buf1; every wave's buf0
    // reads completed before the it=31 barrier (its lgkmcnt(0)), so writing
    // ORed here cannot race another wave's buf0 reads.
    lsum += __shfl_xor(lsum, 32, 64);

    if (nt == 1) {
        if (lane < 32) Lsum[mt * 32 + lane] = lsum;
        #pragma unroll
        for (int dt = 0; dt < 2; ++dt) {
            const int d = dt * 32 + l31;
            #pragma unroll
            for (int g = 0; g < 4; ++g) {
                const int m0 = mt * 32 + 8 * g + 4 * hi;
                const int ph = (m0 >> 2) ^ (d & 15);
                float4 v = { o[dt][4*g+0], o[dt][4*g+1], o[dt][4*g+2], o[dt][4*g+3] };
                *(float4*)&ORed[d * 64 + ph * 4] = v;
            }
        }
    }
    __syncthreads();

    if (nt == 0) {
        float ltot = lsum + Lsum[mt * 32 + l31];
        if (lane < 32) Linv[mt * 32 + lane] = 1.0f / ltot;
        float* Oh = O + ((size_t)bh * SEQ + q0) * HD;
        #pragma unroll
        for (int dt = 0; dt < 2; ++dt) {
            const int d = dt * 32 + l31;
            #pragma unroll
            for (int g = 0; g < 4; ++g) {
                const int m0 = mt * 32 + 8 * g + 4 * hi;
                const int ph = (m0 >> 2) ^ (d & 15);
                float4 part = *(const float4*)&ORed[d * 64 + ph * 4];
                float4 inv4 = *(const float4*)&Linv[m0];
                const float* pp = (const float*)&part;
                const float* ii = (const float*)&inv4;
                #pragma unroll
                for (int j = 0; j < 4; ++j)
                    Oh[(size_t)(m0 + j) * HD + d] = (o[dt][4*g+j] + pp[j]) * ii[j];
            }
        }
    }
}

// ---------------- fallback (no-workspace) kernel ----------------
#define PAD 8
#define LSTR (HD + PAD)

__global__ __launch_bounds__(256)
void fa_fwd_fb(const float* __restrict__ Q, const float* __restrict__ K,
               const float* __restrict__ V, float* __restrict__ O) {
    const int x  = blockIdx.x & 7;
    const int t  = blockIdx.x >> 3;
    const int bh = x + 8 * (t % 3);
    const int qt = t / 3;
    const int q0 = qt * TQ;
    const long base = (long)bh * SEQ * HD;

    __shared__ unsigned short Qs[TQ][LSTR];
    __shared__ unsigned short Ks2[64][LSTR];
    __shared__ unsigned short Vt[HD][64 + PAD];
    __shared__ unsigned short Ps2[4][16][LSTR];

    const int tid  = threadIdx.x;
    const int wave = tid >> 6;
    const int lane = tid & 63;
    const int col  = lane & 15;
    const int quad = lane >> 4;
    const int m0   = wave * 16;

    #pragma unroll
    for (int i = 0; i < 4; ++i) {
        int idx = tid + 256 * i;
        int row = idx >> 4;
        int c4  = (idx & 15) * 4;
        float4 v = *(const float4*)&Q[base + (long)(q0 + row) * HD + c4];
        ushort4 b = { f2bf(v.x), f2bf(v.y), f2bf(v.z), f2bf(v.w) };
        *(ushort4*)&Qs[row][c4] = b;
    }
    __syncthreads();

    bf16x8 aq0 = *(const bf16x8*)&Qs[m0 + col][quad * 8];
    bf16x8 aq1 = *(const bf16x8*)&Qs[m0 + col][32 + quad * 8];

    f32x4 o0 = {0.f,0.f,0.f,0.f}, o1 = o0, o2 = o0, o3 = o0;
    float l[4] = {0.f, 0.f, 0.f, 0.f};
    const float scale = 0.022097086912079608f;

    for (int kv0 = 0; kv0 < SEQ; kv0 += 64) {
        __syncthreads();
        #pragma unroll
        for (int i = 0; i < 4; ++i) {
            int idx = tid + 256 * i;
            int row = idx >> 4;
            int c4  = (idx & 15) * 4;
            float4 kv = *(const float4*)&K[base + (long)(kv0 + row) * HD + c4];
            ushort4 kb = { f2bf(kv.x), f2bf(kv.y), f2bf(kv.z), f2bf(kv.w) };
            *(ushort4*)&Ks2[row][c4] = kb;
            float4 vv = *(const float4*)&V[base + (long)(kv0 + row) * HD + c4];
            Vt[c4 + 0][row] = f2bf(vv.x);
            Vt[c4 + 1][row] = f2bf(vv.y);
            Vt[c4 + 2][row] = f2bf(vv.z);
            Vt[c4 + 3][row] = f2bf(vv.w);
        }
        __syncthreads();

        f32x4 sc[4];
        #pragma unroll
        for (int n = 0; n < 4; ++n) {
            bf16x8 b0 = *(const bf16x8*)&Ks2[n * 16 + col][quad * 8];
            bf16x8 b1 = *(const bf16x8*)&Ks2[n * 16 + col][32 + quad * 8];
            f32x4 acc = {0.f,0.f,0.f,0.f};
            acc = __builtin_amdgcn_mfma_f32_16x16x32_bf16(aq0, b0, acc, 0, 0, 0);
            acc = __builtin_amdgcn_mfma_f32_16x16x32_bf16(aq1, b1, acc, 0, 0, 0);
            sc[n] = acc;
        }

        float tsum[4] = {0.f, 0.f, 0.f, 0.f};
        #pragma unroll
        for (int n = 0; n < 4; ++n) {
            #pragma unroll
            for (int r = 0; r < 4; ++r) {
                float p = __expf(sc[n][r] * scale);
                tsum[r] += p;
                Ps2[wave][quad * 4 + r][n * 16 + col] = f2bf(p);
            }
        }
        #pragma unroll
        for (int off = 1; off < 16; off <<= 1) {
            #pragma unroll
            for (int r = 0; r < 4; ++r) tsum[r] += __shfl_xor(tsum[r], off, 64);
        }
        #pragma unroll
        for (int r = 0; r < 4; ++r) l[r] += tsum[r];

        bf16x8 ap0 = *(const bf16x8*)&Ps2[wave][col][quad * 8];
        bf16x8 ap1 = *(const bf16x8*)&Ps2[wave][col][32 + quad * 8];
        #pragma unroll
        for (int n = 0; n < 4; ++n) {
            bf16x8 b0 = *(const bf16x8*)&Vt[n * 16 + col][quad * 8];
            bf16x8 b1 = *(const bf16x8*)&Vt[n * 16 + col][32 + quad * 8];
            f32x4* op = (n == 0) ? &o0 : (n == 1) ? &o1 : (n == 2) ? &o2 : &o3;
            *op = __builtin_amdgcn_mfma_f32_16x16x32_bf16(ap0, b0, *op, 0, 0, 0);
            *op = __builtin_amdgcn_mfma_f32_16x16x32_bf16(ap1, b1, *op, 0, 0, 0);
        }
    }

    float inv[4];
    #pragma unroll
    for (int r = 0; r < 4; ++r) inv[r] = 1.0f / l[r];
    #pragma unroll
    for (int r = 0; r < 4; ++r) {
        long row = base + (long)(q0 + m0 + quad * 4 + r) * HD;
        O[row +  0 + col] = o0[r] * inv[r];
        O[row + 16 + col] = o1[r] * inv[r];
        O[row + 32 + col] = o2[r] * inv[r];
        O[row + 48 + col] = o3[r] * inv[r];
    }
}

extern "C" void kernel_launch(void* const* d_in, const int* in_sizes, int n_in,
                              void* d_out, int out_size, void* d_ws, size_t ws_size,
                              hipStream_t stream) {
    const float* Q = (const float*)d_in[0];
    const float* K = (const float*)d_in[1];
    const float* V = (const float*)d_in[2];
    float* O = (float*)d_out;

    const size_t tensorElems = (size_t)NHEADS * SEQ * HD;
    const size_t need = 2 * tensorElems * sizeof(unsigned short);

    if (ws_size >= need) {
        unsigned short* Kb  = (unsigned short*)d_ws;
        unsigned short* Vtb = Kb + tensorElems;
        const float qs = (float)(1.4426950408889634 / sqrt(2048.0));  // log2e/sqrt(S)
        prep_kv<<<dim3(NHEADS * (SEQ / 64)), dim3(256), 0, stream>>>(K, V, Kb, Vtb);
        fa_main<<<dim3(NHEADS * (SEQ / TQ)), dim3(256), 0, stream>>>(Q, Kb, Vtb, O, qs);
    } else {
        fa_fwd_fb<<<dim3(NHEADS * (SEQ / TQ)), dim3(256), 0, stream>>>(Q, K, V, O);
    }
}

// Round 7
// 114.985 us; speedup vs baseline: 1.8825x; 1.0211x over previous
//
#include <hip/hip_runtime.h>
#include <hip/hip_bf16.h>
#include <math.h>
#include <stdint.h>

#define BATCH 2
#define NH 12
#define SEQ 2048
#define HD 64
#define TQ 64
#define TK 64
#define NHEADS (BATCH*NH)
#define NIT (SEQ / TK)

typedef short bf16x8 __attribute__((ext_vector_type(8)));
typedef float f32x4 __attribute__((ext_vector_type(4)));
typedef float f32x16 __attribute__((ext_vector_type(16)));
typedef unsigned short us4_t __attribute__((ext_vector_type(4)));
typedef unsigned short us8_t __attribute__((ext_vector_type(8)));
typedef unsigned int u32x4 __attribute__((ext_vector_type(4)));

#if __has_builtin(__builtin_amdgcn_exp2f)
#define EXP2F(x) __builtin_amdgcn_exp2f(x)
#else
#define EXP2F(x) exp2f(x)
#endif

static __device__ __forceinline__ unsigned short f2bf(float f) {
    unsigned int u = __float_as_uint(f);
    u += 0x7fffu + ((u >> 16) & 1u);   // RTNE
    return (unsigned short)(u >> 16);
}

static __device__ __forceinline__ unsigned int pack2bf(float a, float b) {
    __hip_bfloat162 v = __float22bfloat162_rn(float2{a, b});
    return *(unsigned int*)&v;          // low short = a
}

static __device__ __forceinline__ void async_cp16(const void* g, void* l) {
    __builtin_amdgcn_global_load_lds(
        (const __attribute__((address_space(1))) void*)g,
        (__attribute__((address_space(3))) void*)(uintptr_t)l,
        16, 0, 0);
}

// Conflict-free 64x64-bf16 tile layout: 32 row-pairs x 256B, 16 positions of
// 16B, pos = ((r&1)*8 | c) ^ ((r>>1)&15).
static __device__ __forceinline__ int tile_off(int r, int c) {   // shorts, c 0..7
    int rp  = r >> 1;
    int pos = (((r & 1) << 3) | c) ^ (rp & 15);
    return rp * 128 + pos * 8;
}

// ---- pre-pass: K -> bf16 (dense), V -> bf16 transposed [bh][d][s'] where
// s' = s with bits 2<->3 swapped inside each 32-block (pi-permutation that
// makes the S^T C-layout register order equal the PV A-operand order).
__global__ __launch_bounds__(256)
void prep_kv(const float* __restrict__ K, const float* __restrict__ V,
             unsigned short* __restrict__ Kb, unsigned short* __restrict__ Vtb) {
    __shared__ unsigned short T[64][66];
    const int bh = blockIdx.x >> 5;
    const int s0 = (blockIdx.x & 31) * 64;
    const int tid = threadIdx.x;
    const size_t off = ((size_t)bh * SEQ + s0) * HD;

    #pragma unroll
    for (int u = 0; u < 4; ++u) {                 // K: dense 16B loads, 8B stores
        int idx = u * 1024 + tid * 4;
        float4 a = *(const float4*)&K[off + idx];
        us4_t r4 = { f2bf(a.x), f2bf(a.y), f2bf(a.z), f2bf(a.w) };
        *(us4_t*)&Kb[off + idx] = r4;
    }
    #pragma unroll
    for (int u = 0; u < 4; ++u) {                 // V: dense loads -> padded LDS
        int idx = u * 1024 + tid * 4;
        int r = idx >> 6, col = idx & 63;
        float4 a = *(const float4*)&V[off + idx];
        *(unsigned int*)&T[r][col]     = pack2bf(a.x, a.y);
        *(unsigned int*)&T[r][col + 2] = pack2bf(a.z, a.w);
    }
    __syncthreads();
    unsigned short* Vdst = Vtb + (size_t)bh * HD * SEQ;
    const int g = tid & 7, dd = tid >> 3;         // dd 0..31
    #pragma unroll
    for (int h = 0; h < 2; ++h) {
        int d = dd + 32 * h;
        us8_t r8;
        #pragma unroll
        for (int j = 0; j < 8; ++j) {
            // pi: swap bits 2,3 of the 64-local column index (g*8 + j)
            int src = ((g >> 1) << 4) + ((j >> 2) << 3) + ((g & 1) << 2) + (j & 3);
            r8[j] = T[src][d];
        }
        *(us8_t*)&Vdst[(size_t)d * SEQ + s0 + g * 8] = r8;
    }
}

// ---------------- main flash-attention kernel (32x32x16 MFMA) ----------------
// R13 = R9 (best measured fa_main: tri-buffered staging, prefetch distance 2,
// counted vmcnt(4) — R12's within-family A/B proved these worth ~20 us vs
// dbuf+drain) with one change: the iteration body is reordered to
//   barrier -> issue ALL 8 ds_reads (kfc[] + vfc[]) -> issue gl_lds prefetch
//   -> FIN(t-1) (register-only, ~300 cyc, fills the ds_read latency shadow)
//   -> QK(t) on the pre-read fragments.
// In R9 source order QK came first, so its first MFMA serially ate the ds_read
// latency, and FIN ran after.
__global__ __launch_bounds__(256, 3)
void fa_main(const float* __restrict__ Q,
             const unsigned short* __restrict__ Kb,
             const unsigned short* __restrict__ Vtb,
             float* __restrict__ O, float qs) {
    const int x  = blockIdx.x & 7;
    const int t  = blockIdx.x >> 3;
    const int bh = x + 8 * (t % 3);
    const int qt = t / 3;
    const int q0 = qt * TQ;

    // 3 buffers x (K 8KB + V 8KB) + Lsum/Linv
    __shared__ __align__(16) unsigned char SH[49664];
    float* Lsum = (float*)(SH + 49152);                    // 64 f32
    float* Linv = (float*)(SH + 49408);                    // 64 f32
    float* ORed = (float*)SH;                              // 64x64 f32 overlay (buf0)
    unsigned short* QS = (unsigned short*)(SH + 32768);    // Q staging (buf2 K half)

    const int tid  = threadIdx.x;
    const int w    = tid >> 6;
    const int mt   = w >> 1;
    const int nt   = w & 1;
    const int lane = tid & 63;
    const int l31  = lane & 31;
    const int hi   = lane >> 5;

    const float*          Qh = Q   + ((size_t)bh * SEQ + q0) * HD;
    const unsigned short* Kh = Kb  + (size_t)bh * SEQ * HD;
    const unsigned short* Vh = Vtb + (size_t)bh * HD * SEQ;

    // ---- per-lane staging source offsets (loop-invariant) ----
    int rS[2], cS[2];
    #pragma unroll
    for (int i = 0; i < 2; ++i) {
        int rp = w * 8 + 4 * i + (lane >> 4);
        int lc = (lane & 15) ^ (rp & 15);
        rS[i] = 2 * rp + (lc >> 3);
        cS[i] = lc & 7;
    }
    const int dst0 = (w * 8 + 0) * 128, dst1 = (w * 8 + 4) * 128;  // shorts
    const size_t kG0 = (size_t)rS[0] * HD  + cS[0] * 8;
    const size_t kG1 = (size_t)rS[1] * HD  + cS[1] * 8;
    const size_t vG0 = (size_t)rS[0] * SEQ + cS[0] * 8;
    const size_t vG1 = (size_t)rS[1] * SEQ + cS[1] * 8;

    // ---- prologue: tile 0 -> buf0 (async); Q (fp32 -> scaled bf16) -> QS ----
    {
        unsigned short* K0 = (unsigned short*)(SH);
        unsigned short* V0 = (unsigned short*)(SH + 8192);
        async_cp16(Kh + kG0, &K0[dst0]);
        async_cp16(Kh + kG1, &K0[dst1]);
        async_cp16(Vh + vG0, &V0[dst0]);
        async_cp16(Vh + vG1, &V0[dst1]);
    }
    #pragma unroll
    for (int u = 0; u < 4; ++u) {
        int idx = u * 1024 + tid * 4;
        int r = idx >> 6, col = idx & 63;
        float4 a = *(const float4*)&Qh[idx];
        uint2 pk = { pack2bf(a.x * qs, a.y * qs), pack2bf(a.z * qs, a.w * qs) };
        *(uint2*)&QS[tile_off(r, col >> 3) + (col & 7)] = pk;
    }
    __syncthreads();   // Q staged + tile 0 resident (full drain; prologue only)

    // ---- Q B-fragments (rows mt*32..+32) -> registers; then QS is free ----
    bf16x8 qf[4];
    #pragma unroll
    for (int s = 0; s < 4; ++s)
        qf[s] = *(const bf16x8*)&QS[tile_off(mt * 32 + l31, s * 2 + hi)];
    __syncthreads();   // everyone extracted Q; buf2 may be overwritten later

    // ---- tile 1 -> buf1 (stays in flight across the loop's first barrier) ----
    {
        unsigned short* K1 = (unsigned short*)(SH + 16384);
        unsigned short* V1 = (unsigned short*)(SH + 16384 + 8192);
        async_cp16(Kh + (size_t)TK * HD + kG0, &K1[dst0]);
        async_cp16(Kh + (size_t)TK * HD + kG1, &K1[dst1]);
        async_cp16(Vh + (size_t)TK + vG0,      &V1[dst0]);
        async_cp16(Vh + (size_t)TK + vG1,      &V1[dst1]);
    }

    // ---- hoisted fragment LDS offsets ----
    int kOffL[4], vOffL[2][2];
    #pragma unroll
    for (int s = 0; s < 4; ++s) kOffL[s] = tile_off(nt * 32 + l31, s * 2 + hi);
    #pragma unroll
    for (int dt = 0; dt < 2; ++dt)
        #pragma unroll
        for (int ks = 0; ks < 2; ++ks)
            vOffL[dt][ks] = tile_off(dt * 32 + l31, nt * 4 + ks * 2 + hi);

    f32x16 o[2];
    o[0] = (f32x16)(0.f);
    o[1] = (f32x16)(0.f);
    float lsum = 0.f;

    // deferred finish of a tile: exp2 + pack + PV + lsum (all register-local)
    auto FIN = [&](const f32x16& sp, const bf16x8 (&vp)[2][2]) {
        float e0[8], e1[8];
        #pragma unroll
        for (int r = 0; r < 8; ++r) e0[r] = EXP2F(sp[r]);
        #pragma unroll
        for (int r = 0; r < 8; ++r) e1[r] = EXP2F(sp[8 + r]);
        union { u32x4 d; bf16x8 h; } pu0, pu1;
        pu0.d = (u32x4){ pack2bf(e0[0], e0[1]), pack2bf(e0[2], e0[3]),
                         pack2bf(e0[4], e0[5]), pack2bf(e0[6], e0[7]) };
        pu1.d = (u32x4){ pack2bf(e1[0], e1[1]), pack2bf(e1[2], e1[3]),
                         pack2bf(e1[4], e1[5]), pack2bf(e1[6], e1[7]) };
        bf16x8 pf0 = pu0.h, pf1 = pu1.h;
        o[0] = __builtin_amdgcn_mfma_f32_32x32x16_bf16(pf0, vp[0][0], o[0], 0, 0, 0);
        o[1] = __builtin_amdgcn_mfma_f32_32x32x16_bf16(pf0, vp[1][0], o[1], 0, 0, 0);
        o[0] = __builtin_amdgcn_mfma_f32_32x32x16_bf16(pf1, vp[0][1], o[0], 0, 0, 0);
        o[1] = __builtin_amdgcn_mfma_f32_32x32x16_bf16(pf1, vp[1][1], o[1], 0, 0, 0);
        float t0 = ((e0[0] + e0[1]) + (e0[2] + e0[3]))
                 + ((e0[4] + e0[5]) + (e0[6] + e0[7]));
        float t1 = ((e1[0] + e1[1]) + (e1[2] + e1[3]))
                 + ((e1[4] + e1[5]) + (e1[6] + e1[7]));
        lsum += t0 + t1;
    };

    unsigned int b0 = 0, b1 = 16384, b2 = 32768;   // rotating buffer byte offsets

    // pipeline state: scores + V fragments of the previous tile
    f32x16 scp;
    bf16x8 vfp[2][2];

    // ---- peeled iteration 0: tile 0 resident, all waves synced (prologue) ----
    {
        // prefetch tile 2 into buf2 (overwrites QS — qf already extracted)
        unsigned short* Kn = (unsigned short*)(SH + b2);
        unsigned short* Vn = (unsigned short*)(SH + b2 + 8192);
        async_cp16(Kh + (size_t)2 * TK * HD + kG0, &Kn[dst0]);
        async_cp16(Kh + (size_t)2 * TK * HD + kG1, &Kn[dst1]);
        async_cp16(Vh + (size_t)2 * TK + vG0,      &Vn[dst0]);
        async_cp16(Vh + (size_t)2 * TK + vG1,      &Vn[dst1]);

        const unsigned short* Ks = (const unsigned short*)(SH + b0);
        const unsigned short* Vs = (const unsigned short*)(SH + b0 + 8192);
        #pragma unroll
        for (int dt = 0; dt < 2; ++dt)
            #pragma unroll
            for (int ks = 0; ks < 2; ++ks)
                vfp[dt][ks] = *(const bf16x8*)&Vs[vOffL[dt][ks]];
        f32x16 sc = (f32x16)(0.f);
        #pragma unroll
        for (int s = 0; s < 4; ++s) {
            bf16x8 kf = *(const bf16x8*)&Ks[kOffL[s]];
            sc = __builtin_amdgcn_mfma_f32_32x32x16_bf16(kf, qf[s], sc, 0, 0, 0);
        }
        scp = sc;
        unsigned int btmp = b0; b0 = b1; b1 = b2; b2 = btmp;
    }

    // ---- main loop: iter t = {ds_reads(t) -> FIN(t-1) in their shadow -> QK(t)}
    #pragma unroll 2
    for (int it = 1; it < NIT; ++it) {
        // all my ds_reads (incl. deferred V frags) complete before the barrier,
        // so the post-barrier prefetch into buf[(it+2)%3] cannot race them.
        asm volatile("s_waitcnt lgkmcnt(0)" ::: "memory");
        if (it == NIT - 1) { asm volatile("s_waitcnt vmcnt(0)" ::: "memory"); }
        else               { asm volatile("s_waitcnt vmcnt(4)" ::: "memory"); }
        __builtin_amdgcn_s_barrier();   // all waves: tile it resident

        const unsigned short* Ks = (const unsigned short*)(SH + b0);
        const unsigned short* Vs = (const unsigned short*)(SH + b0 + 8192);

        // ---- issue ALL fragment ds_reads for tile it up front ----
        bf16x8 kfc[4];
        #pragma unroll
        for (int s = 0; s < 4; ++s)
            kfc[s] = *(const bf16x8*)&Ks[kOffL[s]];
        bf16x8 vfc[2][2];
        #pragma unroll
        for (int dt = 0; dt < 2; ++dt)
            #pragma unroll
            for (int ks = 0; ks < 2; ++ks)
                vfc[dt][ks] = *(const bf16x8*)&Vs[vOffL[dt][ks]];

        if (it + 2 < NIT) {            // prefetch tile it+2 into rotating buffer
            const size_t kv = (size_t)(it + 2) * TK;
            unsigned short* Kn = (unsigned short*)(SH + b2);
            unsigned short* Vn = (unsigned short*)(SH + b2 + 8192);
            async_cp16(Kh + kv * HD + kG0, &Kn[dst0]);
            async_cp16(Kh + kv * HD + kG1, &Kn[dst1]);
            async_cp16(Vh + kv + vG0,      &Vn[dst0]);
            async_cp16(Vh + kv + vG1,      &Vn[dst1]);
        }

        // ---- FIN(it-1): register-only, runs in the ds_read latency shadow ----
        FIN(scp, vfp);

        // ---- QK MFMAs for tile it on the pre-read fragments ----
        f32x16 scc = (f32x16)(0.f);
        #pragma unroll
        for (int s = 0; s < 4; ++s)
            scc = __builtin_amdgcn_mfma_f32_32x32x16_bf16(kfc[s], qf[s], scc, 0, 0, 0);

        scp = scc;
        #pragma unroll
        for (int dt = 0; dt < 2; ++dt)
            #pragma unroll
            for (int ks = 0; ks < 2; ++ks)
                vfp[dt][ks] = vfc[dt][ks];

        unsigned int btmp = b0; b0 = b1; b1 = b2; b2 = btmp;
    }

    // ---- tail: finish the last tile ----
    FIN(scp, vfp);

    // ---- epilogue: combine nt partials (O and lsum), normalize, store ----
    // ORed overlays buf0; last iter's reads/prefetches touch buf1 only.
    lsum += __shfl_xor(lsum, 32, 64);

    if (nt == 1) {
        if (lane < 32) Lsum[mt * 32 + lane] = lsum;
        #pragma unroll
        for (int dt = 0; dt < 2; ++dt) {
            const int d = dt * 32 + l31;
            #pragma unroll
            for (int g = 0; g < 4; ++g) {
                const int m0 = mt * 32 + 8 * g + 4 * hi;
                const int ph = (m0 >> 2) ^ (d & 15);
                float4 v = { o[dt][4*g+0], o[dt][4*g+1], o[dt][4*g+2], o[dt][4*g+3] };
                *(float4*)&ORed[d * 64 + ph * 4] = v;
            }
        }
    }
    __syncthreads();

    if (nt == 0) {
        float ltot = lsum + Lsum[mt * 32 + l31];
        if (lane < 32) Linv[mt * 32 + lane] = 1.0f / ltot;
        float* Oh = O + ((size_t)bh * SEQ + q0) * HD;
        #pragma unroll
        for (int dt = 0; dt < 2; ++dt) {
            const int d = dt * 32 + l31;
            #pragma unroll
            for (int g = 0; g < 4; ++g) {
                const int m0 = mt * 32 + 8 * g + 4 * hi;
                const int ph = (m0 >> 2) ^ (d & 15);
                float4 part = *(const float4*)&ORed[d * 64 + ph * 4];
                float4 inv4 = *(const float4*)&Linv[m0];
                const float* pp = (const float*)&part;
                const float* ii = (const float*)&inv4;
                #pragma unroll
                for (int j = 0; j < 4; ++j)
                    Oh[(size_t)(m0 + j) * HD + d] = (o[dt][4*g+j] + pp[j]) * ii[j];
            }
        }
    }
}

// ---------------- fallback (no-workspace) kernel ----------------
#define PAD 8
#define LSTR (HD + PAD)

__global__ __launch_bounds__(256)
void fa_fwd_fb(const float* __restrict__ Q, const float* __restrict__ K,
               const float* __restrict__ V, float* __restrict__ O) {
    const int x  = blockIdx.x & 7;
    const int t  = blockIdx.x >> 3;
    const int bh = x + 8 * (t % 3);
    const int qt = t / 3;
    const int q0 = qt * TQ;
    const long base = (long)bh * SEQ * HD;

    __shared__ unsigned short Qs[TQ][LSTR];
    __shared__ unsigned short Ks2[64][LSTR];
    __shared__ unsigned short Vt[HD][64 + PAD];
    __shared__ unsigned short Ps2[4][16][LSTR];

    const int tid  = threadIdx.x;
    const int wave = tid >> 6;
    const int lane = tid & 63;
    const int col  = lane & 15;
    const int quad = lane >> 4;
    const int m0   = wave * 16;

    #pragma unroll
    for (int i = 0; i < 4; ++i) {
        int idx = tid + 256 * i;
        int row = idx >> 4;
        int c4  = (idx & 15) * 4;
        float4 v = *(const float4*)&Q[base + (long)(q0 + row) * HD + c4];
        ushort4 b = { f2bf(v.x), f2bf(v.y), f2bf(v.z), f2bf(v.w) };
        *(ushort4*)&Qs[row][c4] = b;
    }
    __syncthreads();

    bf16x8 aq0 = *(const bf16x8*)&Qs[m0 + col][quad * 8];
    bf16x8 aq1 = *(const bf16x8*)&Qs[m0 + col][32 + quad * 8];

    f32x4 o0 = {0.f,0.f,0.f,0.f}, o1 = o0, o2 = o0, o3 = o0;
    float l[4] = {0.f, 0.f, 0.f, 0.f};
    const float scale = 0.022097086912079608f;

    for (int kv0 = 0; kv0 < SEQ; kv0 += 64) {
        __syncthreads();
        #pragma unroll
        for (int i = 0; i < 4; ++i) {
            int idx = tid + 256 * i;
            int row = idx >> 4;
            int c4  = (idx & 15) * 4;
            float4 kv = *(const float4*)&K[base + (long)(kv0 + row) * HD + c4];
            ushort4 kb = { f2bf(kv.x), f2bf(kv.y), f2bf(kv.z), f2bf(kv.w) };
            *(ushort4*)&Ks2[row][c4] = kb;
            float4 vv = *(const float4*)&V[base + (long)(kv0 + row) * HD + c4];
            Vt[c4 + 0][row] = f2bf(vv.x);
            Vt[c4 + 1][row] = f2bf(vv.y);
            Vt[c4 + 2][row] = f2bf(vv.z);
            Vt[c4 + 3][row] = f2bf(vv.w);
        }
        __syncthreads();

        f32x4 sc[4];
        #pragma unroll
        for (int n = 0; n < 4; ++n) {
            bf16x8 b0 = *(const bf16x8*)&Ks2[n * 16 + col][quad * 8];
            bf16x8 b1 = *(const bf16x8*)&Ks2[n * 16 + col][32 + quad * 8];
            f32x4 acc = {0.f,0.f,0.f,0.f};
            acc = __builtin_amdgcn_mfma_f32_16x16x32_bf16(aq0, b0, acc, 0, 0, 0);
            acc = __builtin_amdgcn_mfma_f32_16x16x32_bf16(aq1, b1, acc, 0, 0, 0);
            sc[n] = acc;
        }

        float tsum[4] = {0.f, 0.f, 0.f, 0.f};
        #pragma unroll
        for (int n = 0; n < 4; ++n) {
            #pragma unroll
            for (int r = 0; r < 4; ++r) {
                float p = __expf(sc[n][r] * scale);
                tsum[r] += p;
                Ps2[wave][quad * 4 + r][n * 16 + col] = f2bf(p);
            }
        }
        #pragma unroll
        for (int off = 1; off < 16; off <<= 1) {
            #pragma unroll
            for (int r = 0; r < 4; ++r) tsum[r] += __shfl_xor(tsum[r], off, 64);
        }
        #pragma unroll
        for (int r = 0; r < 4; ++r) l[r] += tsum[r];

        bf16x8 ap0 = *(const bf16x8*)&Ps2[wave][col][quad * 8];
        bf16x8 ap1 = *(const bf16x8*)&Ps2[wave][col][32 + quad * 8];
        #pragma unroll
        for (int n = 0; n < 4; ++n) {
            bf16x8 b0 = *(const bf16x8*)&Vt[n * 16 + col][quad * 8];
            bf16x8 b1 = *(const bf16x8*)&Vt[n * 16 + col][32 + quad * 8];
            f32x4* op = (n == 0) ? &o0 : (n == 1) ? &o1 : (n == 2) ? &o2 : &o3;
            *op = __builtin_amdgcn_mfma_f32_16x16x32_bf16(ap0, b0, *op, 0, 0, 0);
            *op = __builtin_amdgcn_mfma_f32_16x16x32_bf16(ap1, b1, *op, 0, 0, 0);
        }
    }

    float inv[4];
    #pragma unroll
    for (int r = 0; r < 4; ++r) inv[r] = 1.0f / l[r];
    #pragma unroll
    for (int r = 0; r < 4; ++r) {
        long row = base + (long)(q0 + m0 + quad * 4 + r) * HD;
        O[row +  0 + col] = o0[r] * inv[r];
        O[row + 16 + col] = o1[r] * inv[r];
        O[row + 32 + col] = o2[r] * inv[r];
        O[row + 48 + col] = o3[r] * inv[r];
    }
}

extern "C" void kernel_launch(void* const* d_in, const int* in_sizes, int n_in,
                              void* d_out, int out_size, void* d_ws, size_t ws_size,
                              hipStream_t stream) {
    const float* Q = (const float*)d_in[0];
    const float* K = (const float*)d_in[1];
    const float* V = (const float*)d_in[2];
    float* O = (float*)d_out;

    const size_t tensorElems = (size_t)NHEADS * SEQ * HD;
    const size_t need = 2 * tensorElems * sizeof(unsigned short);

    if (ws_size >= need) {
        unsigned short* Kb  = (unsigned short*)d_ws;
        unsigned short* Vtb = Kb + tensorElems;
        const float qs = (float)(1.4426950408889634 / sqrt(2048.0));  // log2e/sqrt(S)
        prep_kv<<<dim3(NHEADS * (SEQ / 64)), dim3(256), 0, stream>>>(K, V, Kb, Vtb);
        fa_main<<<dim3(NHEADS * (SEQ / TQ)), dim3(256), 0, stream>>>(Q, Kb, Vtb, O, qs);
    } else {
        fa_fwd_fb<<<dim3(NHEADS * (SEQ / TQ)), dim3(256), 0, stream>>>(Q, K, V, O);
    }
}